// Round 1
// baseline (582.820 us; speedup 1.0000x reference)
//
#include <hip/hip_runtime.h>
#include <hip/hip_bf16.h>
#include <stdint.h>

#define B_DIM 256
#define I_DIM 128
#define C_DIM 1024
#define U_DIM 32
#define S_DIM 16
#define N_DIM 512            // U*S
#define KC    (C_DIM * I_DIM)   // 131072, row length of xT per b

typedef __bf16 bf16;
typedef __attribute__((ext_vector_type(8))) __bf16 bf16x8;
typedef __attribute__((ext_vector_type(4))) float f32x4;

// ---------------------------------------------------------------------------
// async global->LDS, 16B per lane. LDS dest is wave-uniform-base + lane*16;
// our staging pattern is constructed so linear LDS offset == tid*16 exactly.
// ---------------------------------------------------------------------------
__device__ __forceinline__ void async_copy16(const bf16* g, short* l) {
  __builtin_amdgcn_global_load_lds(
      (const __attribute__((address_space(1))) uint32_t*)g,
      (__attribute__((address_space(3))) uint32_t*)l, 16, 0, 0);
}

// ---------------------------------------------------------------------------
// Kernel 1: xT[b][c][i] = (bf16) x[b][i][c]
// 64x64 tiles, coalesced fp32 loads (contig over c), coalesced bf16 stores
// (contig over i). LDS pad 65 keeps the transposed read conflict-free.
// ---------------------------------------------------------------------------
__global__ void __launch_bounds__(256)
transpose_cast(const float* __restrict__ x, bf16* __restrict__ xT) {
  __shared__ float tile[64][65];
  const int c0 = blockIdx.x * 64;
  const int i0 = blockIdx.y * 64;
  const int b  = blockIdx.z;
  const int t  = threadIdx.x;
  const int cl = t & 63;
  const int ib = t >> 6;                 // 0..3
  const float* xb = x + (size_t)b * (I_DIM * C_DIM);
#pragma unroll
  for (int r = 0; r < 16; ++r) {
    const int il = r * 4 + ib;
    tile[il][cl] = xb[(size_t)(i0 + il) * C_DIM + c0 + cl];
  }
  __syncthreads();
  bf16* xTb = xT + (size_t)b * KC;
#pragma unroll
  for (int r = 0; r < 16; ++r) {
    const int clr = r * 4 + ib;
    // xT[b][c0+clr][i0+cl] = x[b][i0+cl][c0+clr]
    xTb[(size_t)(c0 + clr) * I_DIM + i0 + cl] = (bf16)tile[cl][clr];
  }
}

// ---------------------------------------------------------------------------
// Kernel 2: split-K GEMM.  s_j[b][n] += sum_{c in chunk} sum_i
//                          xT[b][c][i] * W[c][n][i],  n = u*16+s.
// Block: 512 thr (8 waves as 4m x 2n), M=256 (full), N-tile=128, 16 c per
// block. A (xT) staged in LDS via global_load_lds w/ xor-swizzled 16B chunks;
// W loaded straight to registers (lane reads 8 contiguous fp32) + cvt bf16.
// ---------------------------------------------------------------------------
__global__ void __launch_bounds__(512)
gemm_kernel(const bf16* __restrict__ xT, const float* __restrict__ W,
            float* __restrict__ sj) {
  __shared__ short Alds[B_DIM * I_DIM];   // 256 rows x 128 bf16 = 64 KB
  const int tid  = threadIdx.x;
  const int lane = tid & 63;
  const int wave = tid >> 6;              // 0..7
  const int wm   = wave >> 1;             // 0..3 -> m base = wm*64
  const int wn   = wave & 1;              // 0..1 -> n base = n0 + wn*64
  const int l15  = lane & 15;
  const int lq   = lane >> 4;             // 0..3
  const int n0   = blockIdx.x * 128;
  const int c0   = blockIdx.y * 16;

  const int row_st   = tid >> 4;          // 0..31 (row within an 8KB round)
  const int chunk_st = tid & 15;          // stored 16B-chunk index

  f32x4 acc[4][4] = {};                   // 64 VGPRs accumulator / lane

  for (int cc = 0; cc < 16; ++cc) {
    const int c = c0 + cc;
    __syncthreads();                      // previous iter done reading Alds
    // ---- stage A: xT[:, c, 0:128] -> Alds, 8 rounds x 8KB ----
#pragma unroll
    for (int r = 0; r < 8; ++r) {
      const int m    = r * 32 + row_st;
      const int csrc = chunk_st ^ (m & 15);       // xor-swizzle source chunk
      const bf16* g  = xT + (size_t)m * KC + (size_t)c * I_DIM + csrc * 8;
      async_copy16(g, &Alds[m * I_DIM + chunk_st * 8]);
    }
    __syncthreads();                      // drains vmcnt before barrier

    const float* Wc = W + (size_t)c * (N_DIM * I_DIM);
#pragma unroll
    for (int ks = 0; ks < 4; ++ks) {
      const int i0 = ks * 32;
      // A fragments from LDS (swizzled; 2-way bank alias only -> free)
      bf16x8 a[4];
#pragma unroll
      for (int mt = 0; mt < 4; ++mt) {
        const int m  = wm * 64 + mt * 16 + l15;
        const int st = ((i0 >> 3) + lq) ^ l15;    // m&15 == l15 here
        a[mt] = *(const bf16x8*)&Alds[m * I_DIM + st * 8];
      }
      // B fragments direct from global W (fp32 -> bf16 in regs)
      bf16x8 b[4];
#pragma unroll
      for (int nt = 0; nt < 4; ++nt) {
        const int n = n0 + wn * 64 + nt * 16 + l15;
        const float* wp = Wc + (size_t)n * I_DIM + i0 + lq * 8;
        const float4 w0 = *(const float4*)(wp);
        const float4 w1 = *(const float4*)(wp + 4);
        bf16x8 bb;
        bb[0] = (bf16)w0.x; bb[1] = (bf16)w0.y;
        bb[2] = (bf16)w0.z; bb[3] = (bf16)w0.w;
        bb[4] = (bf16)w1.x; bb[5] = (bf16)w1.y;
        bb[6] = (bf16)w1.z; bb[7] = (bf16)w1.w;
        b[nt] = bb;
      }
#pragma unroll
      for (int mt = 0; mt < 4; ++mt)
#pragma unroll
        for (int nt = 0; nt < 4; ++nt)
          acc[mt][nt] = __builtin_amdgcn_mfma_f32_16x16x32_bf16(
              a[mt], b[nt], acc[mt][nt], 0, 0, 0);
    }
  }

  // ---- epilogue: fold split-K partial into s_j ----
  // D layout: row = lq*4 + reg, col = l15  (m89-verified)
#pragma unroll
  for (int mt = 0; mt < 4; ++mt) {
#pragma unroll
    for (int nt = 0; nt < 4; ++nt) {
      const int n = n0 + wn * 64 + nt * 16 + l15;
#pragma unroll
      for (int r = 0; r < 4; ++r) {
        const int brow = wm * 64 + mt * 16 + lq * 4 + r;
        atomicAdd(&sj[(size_t)brow * N_DIM + n], acc[mt][nt][r]);
      }
    }
  }
}

// ---------------------------------------------------------------------------
// Kernel 3: squash.  per (b,s): msq = sum_u s^2 ; v = s * sqrt(msq)/(1+msq)
// One block per b; n = u*16+s, reduction over u = stride-16 tree fold.
// ---------------------------------------------------------------------------
__global__ void __launch_bounds__(512)
squash_kernel(const float* __restrict__ sj, float* __restrict__ out) {
  __shared__ float sm[512];
  const int b = blockIdx.x;
  const int t = threadIdx.x;
  const float v = sj[(size_t)b * N_DIM + t];
  sm[t] = v * v;
  __syncthreads();
#pragma unroll
  for (int off = 256; off >= 16; off >>= 1) {
    if (t < off) sm[t] += sm[t + off];
    __syncthreads();
  }
  const float msq   = sm[t & 15];
  const float scale = sqrtf(msq) / (1.0f + msq);
  out[(size_t)b * N_DIM + t] = v * scale;
}

// ---------------------------------------------------------------------------
extern "C" void kernel_launch(void* const* d_in, const int* in_sizes, int n_in,
                              void* d_out, int out_size, void* d_ws, size_t ws_size,
                              hipStream_t stream) {
  const float* x = (const float*)d_in[0];   // (256,128,1024) fp32
  const float* W = (const float*)d_in[1];   // (1,1024,32,16,128) fp32
  float* out = (float*)d_out;               // (256,32,16,1) fp32

  bf16*  xT = (bf16*)d_ws;                                  // 64 MiB
  float* sj = (float*)((char*)d_ws + (size_t)B_DIM * KC * sizeof(bf16));

  hipMemsetAsync(sj, 0, (size_t)B_DIM * N_DIM * sizeof(float), stream);
  transpose_cast<<<dim3(C_DIM / 64, I_DIM / 64, B_DIM), 256, 0, stream>>>(x, xT);
  gemm_kernel<<<dim3(4, 64), 512, 0, stream>>>(xT, W, sj);
  squash_kernel<<<B_DIM, 512, 0, stream>>>(sj, out);
}

// Round 2
// 550.228 us; speedup vs baseline: 1.0592x; 1.0592x over previous
//
#include <hip/hip_runtime.h>
#include <hip/hip_bf16.h>
#include <stdint.h>

#define B_DIM 256
#define I_DIM 128
#define C_DIM 1024
#define N_DIM 512            // U*S
#define KC    (C_DIM * I_DIM)

typedef __bf16 bf16;
typedef __attribute__((ext_vector_type(4))) __bf16 bf16x4;
typedef __attribute__((ext_vector_type(8))) __bf16 bf16x8;
typedef __attribute__((ext_vector_type(4))) float f32x4;

__device__ __forceinline__ void async_copy16(const bf16* g, short* l) {
  __builtin_amdgcn_global_load_lds(
      (const __attribute__((address_space(1))) uint32_t*)g,
      (__attribute__((address_space(3))) uint32_t*)l, 16, 0, 0);
}

// ---------------------------------------------------------------------------
// Kernel 1: xT[b][c][i] = (bf16) x[b][i][c].  64x64 tiles.
// Load: float4 over c (1 KB/wave).  Store: bf16x4 over i (512 B/wave).
// LDS stride 65: both access phases are exactly 2-way bank-aliased (free).
// ---------------------------------------------------------------------------
__global__ void __launch_bounds__(256)
transpose_cast(const float* __restrict__ x, bf16* __restrict__ xT) {
  __shared__ float tile[64][65];
  const int c0 = blockIdx.x * 64;
  const int i0 = blockIdx.y * 64;
  const int b  = blockIdx.z;
  const int t  = threadIdx.x;
  const int sub = t >> 4;               // 0..15
  const int cg  = t & 15;               // 0..15
  const float* xb = x + (size_t)b * (I_DIM * C_DIM);
#pragma unroll
  for (int r = 0; r < 4; ++r) {
    const int i = r * 16 + sub;
    const float4 v = *(const float4*)&xb[(size_t)(i0 + i) * C_DIM + c0 + cg * 4];
    tile[i][cg * 4 + 0] = v.x; tile[i][cg * 4 + 1] = v.y;
    tile[i][cg * 4 + 2] = v.z; tile[i][cg * 4 + 3] = v.w;
  }
  __syncthreads();
  bf16* xTb = xT + (size_t)b * KC;
#pragma unroll
  for (int r = 0; r < 4; ++r) {
    const int c = r * 16 + sub;
    bf16x4 o;
    o[0] = (bf16)tile[cg * 4 + 0][c];
    o[1] = (bf16)tile[cg * 4 + 1][c];
    o[2] = (bf16)tile[cg * 4 + 2][c];
    o[3] = (bf16)tile[cg * 4 + 3][c];
    *(bf16x4*)&xTb[(size_t)(c0 + c) * I_DIM + i0 + cg * 4] = o;
  }
}

// ---------------------------------------------------------------------------
// Kernel 2: split-K GEMM.  s_j[b][n] += sum_{c in chunk} sum_i
//   xT[b][c][i] * W[c][n][i].
// Block: 512 thr (8 waves, 4m x 2n), M=256 (full -> W streamed once),
// N-tile=64, 16 c per block -> grid (8,64)=512 blocks = 2 blocks/CU.
// Per-wave: 4m x 2n frags -> acc = 32 AGPR; total regs ~112 <= 128 so both
// blocks are resident (16 waves/CU).  W double-buffered in registers one ks
// ahead (fine-grained vmcnt); ks=0's W issued before the staging barrier.
// ---------------------------------------------------------------------------
__global__ void __launch_bounds__(512, 4)
gemm_kernel(const bf16* __restrict__ xT, const float* __restrict__ W,
            float* __restrict__ sj) {
  __shared__ short Alds[B_DIM * I_DIM];   // 64 KB
  const int tid  = threadIdx.x;
  const int lane = tid & 63;
  const int wave = tid >> 6;              // 0..7
  const int wm   = wave >> 1;             // 0..3 -> m base wm*64
  const int wn   = wave & 1;              // 0..1 -> n base n0 + wn*32
  const int l15  = lane & 15;
  const int lq   = lane >> 4;             // 0..3
  const int n0   = blockIdx.x * 64;
  const int c0   = blockIdx.y * 16;
  const int row_st   = tid >> 4;          // 0..31
  const int chunk_st = tid & 15;

  f32x4 acc[4][2] = {};                   // 32 AGPRs

  for (int cc = 0; cc < 16; ++cc) {
    const int c = c0 + cc;
    const float* Wc = W + (size_t)c * (N_DIM * I_DIM);
    __syncthreads();                      // prev iter done reading Alds

    // prefetch W for ks=0 (lands during the staging drain below)
    float4 wraw[2][2][2];
#pragma unroll
    for (int nt = 0; nt < 2; ++nt) {
      const float* wp = Wc + (size_t)(n0 + wn * 32 + nt * 16 + l15) * I_DIM + lq * 8;
      wraw[0][nt][0] = *(const float4*)wp;
      wraw[0][nt][1] = *(const float4*)(wp + 4);
    }

    // stage A: xT[:, c, 0:128] -> Alds (xor-swizzled 16B chunks)
#pragma unroll
    for (int r = 0; r < 8; ++r) {
      const int m    = r * 32 + row_st;
      const int csrc = chunk_st ^ (m & 15);
      const bf16* g  = xT + (size_t)m * KC + (size_t)c * I_DIM + csrc * 8;
      async_copy16(g, &Alds[m * I_DIM + chunk_st * 8]);
    }
    __syncthreads();

#pragma unroll
    for (int ks = 0; ks < 4; ++ks) {
      const int cur = ks & 1;
      if (ks < 3) {                       // prefetch next ks's W
        const int i0n = (ks + 1) * 32;
#pragma unroll
        for (int nt = 0; nt < 2; ++nt) {
          const float* wp = Wc + (size_t)(n0 + wn * 32 + nt * 16 + l15) * I_DIM + i0n + lq * 8;
          wraw[cur ^ 1][nt][0] = *(const float4*)wp;
          wraw[cur ^ 1][nt][1] = *(const float4*)(wp + 4);
        }
      }
      const int i0 = ks * 32;
      bf16x8 a[4];
#pragma unroll
      for (int mt = 0; mt < 4; ++mt) {
        const int m  = wm * 64 + mt * 16 + l15;
        const int st = ((i0 >> 3) + lq) ^ l15;   // m&15 == l15
        a[mt] = *(const bf16x8*)&Alds[m * I_DIM + st * 8];
      }
      bf16x8 b[2];
#pragma unroll
      for (int nt = 0; nt < 2; ++nt) {
        const float4 w0 = wraw[cur][nt][0];
        const float4 w1 = wraw[cur][nt][1];
        bf16x8 bb;
        bb[0] = (bf16)w0.x; bb[1] = (bf16)w0.y;
        bb[2] = (bf16)w0.z; bb[3] = (bf16)w0.w;
        bb[4] = (bf16)w1.x; bb[5] = (bf16)w1.y;
        bb[6] = (bf16)w1.z; bb[7] = (bf16)w1.w;
        b[nt] = bb;
      }
#pragma unroll
      for (int mt = 0; mt < 4; ++mt)
#pragma unroll
        for (int nt = 0; nt < 2; ++nt)
          acc[mt][nt] = __builtin_amdgcn_mfma_f32_16x16x32_bf16(
              a[mt], b[nt], acc[mt][nt], 0, 0, 0);
    }
  }

  // epilogue: fold split-K partial into s_j (D layout: row=lq*4+r, col=l15)
#pragma unroll
  for (int mt = 0; mt < 4; ++mt) {
#pragma unroll
    for (int nt = 0; nt < 2; ++nt) {
      const int n = n0 + wn * 32 + nt * 16 + l15;
#pragma unroll
      for (int r = 0; r < 4; ++r) {
        const int brow = wm * 64 + mt * 16 + lq * 4 + r;
        atomicAdd(&sj[(size_t)brow * N_DIM + n], acc[mt][nt][r]);
      }
    }
  }
}

// ---------------------------------------------------------------------------
// Kernel 3: squash.  per (b,s): msq = sum_u s^2 ; v = s * sqrt(msq)/(1+msq)
// ---------------------------------------------------------------------------
__global__ void __launch_bounds__(512)
squash_kernel(const float* __restrict__ sj, float* __restrict__ out) {
  __shared__ float sm[512];
  const int b = blockIdx.x;
  const int t = threadIdx.x;
  const float v = sj[(size_t)b * N_DIM + t];
  sm[t] = v * v;
  __syncthreads();
#pragma unroll
  for (int off = 256; off >= 16; off >>= 1) {
    if (t < off) sm[t] += sm[t + off];
    __syncthreads();
  }
  const float msq   = sm[t & 15];
  const float scale = sqrtf(msq) / (1.0f + msq);
  out[(size_t)b * N_DIM + t] = v * scale;
}

// ---------------------------------------------------------------------------
extern "C" void kernel_launch(void* const* d_in, const int* in_sizes, int n_in,
                              void* d_out, int out_size, void* d_ws, size_t ws_size,
                              hipStream_t stream) {
  const float* x = (const float*)d_in[0];   // (256,128,1024) fp32
  const float* W = (const float*)d_in[1];   // (1,1024,32,16,128) fp32
  float* out = (float*)d_out;               // (256,32,16,1) fp32

  bf16*  xT = (bf16*)d_ws;                                  // 64 MiB
  float* sj = (float*)((char*)d_ws + (size_t)B_DIM * KC * sizeof(bf16));

  hipMemsetAsync(sj, 0, (size_t)B_DIM * N_DIM * sizeof(float), stream);
  transpose_cast<<<dim3(C_DIM / 64, I_DIM / 64, B_DIM), 256, 0, stream>>>(x, xT);
  gemm_kernel<<<dim3(8, 64), 512, 0, stream>>>(xT, W, sj);
  squash_kernel<<<B_DIM, 512, 0, stream>>>(sj, out);
}